// Round 1
// baseline (1550.886 us; speedup 1.0000x reference)
//
#include <hip/hip_runtime.h>
#include <hip/hip_bf16.h>
#include <stdint.h>

typedef __hip_bfloat16 bf16;

#define NIMG 40      // B*T
#define TFR  5
#define CIN  3
#define FCH  64
#define HH   64
#define WW   64
#define HW   4096
#define PX   32      // pixels per dcn block
#define SVS  584     // sv row stride in bf16 (576 data + pad, keeps b128 conflict-free)

__device__ __forceinline__ float bf2f(bf16 v){ return __bfloat162float(v); }

// ---------------- K1: feat = prelu(conv3x3(x, W_init)) ----------------
__global__ __launch_bounds__(256) void k_feat(
    const float* __restrict__ x, const float* __restrict__ Wi,
    const float* __restrict__ bi, const float* __restrict__ ai,
    bf16* __restrict__ feat)
{
  int idx = blockIdx.x*256 + threadIdx.x;     // n*F*HW + f*HW + p
  int p = idx & (HW-1);
  int f = (idx >> 12) & 63;
  int n = idx >> 18;
  int h = p >> 6, w = p & 63;
  const float* xin = x + (size_t)n*(CIN*HW);
  const float* wf  = Wi + f*(CIN*9);
  float acc = bi[f];
  #pragma unroll
  for (int c = 0; c < CIN; ++c) {
    #pragma unroll
    for (int ky = 0; ky < 3; ++ky) {
      int yy = h + ky - 1;
      if (yy < 0 || yy >= HH) continue;
      #pragma unroll
      for (int kx = 0; kx < 3; ++kx) {
        int xx = w + kx - 1;
        if (xx < 0 || xx >= WW) continue;
        acc += xin[c*HW + yy*WW + xx] * wf[c*9 + ky*3 + kx];
      }
    }
  }
  float a = ai[f];
  acc = acc >= 0.f ? acc : a*acc;
  feat[idx] = __float2bfloat16(acc);
}

// ---------------- K2: off_feat = prelu(conv3x3(concat(ref0, x), W_off)) ----------------
__global__ __launch_bounds__(256) void k_offfeat(
    const float* __restrict__ x, const float* __restrict__ Wo,
    const float* __restrict__ bo, const float* __restrict__ ao,
    bf16* __restrict__ offf)
{
  int idx = blockIdx.x*256 + threadIdx.x;
  int p = idx & (HW-1);
  int f = (idx >> 12) & 63;
  int n = idx >> 18;
  int h = p >> 6, w = p & 63;
  int n0 = (n/TFR)*TFR;                       // reference frame (t=0) of this clip
  const float* xr = x + (size_t)n0*(CIN*HW);
  const float* xc = x + (size_t)n *(CIN*HW);
  const float* wf = Wo + f*(6*9);
  float acc = bo[f];
  #pragma unroll
  for (int c = 0; c < 6; ++c) {
    const float* src = (c < 3) ? (xr + c*HW) : (xc + (c-3)*HW);
    #pragma unroll
    for (int ky = 0; ky < 3; ++ky) {
      int yy = h + ky - 1;
      if (yy < 0 || yy >= HH) continue;
      #pragma unroll
      for (int kx = 0; kx < 3; ++kx) {
        int xx = w + kx - 1;
        if (xx < 0 || xx >= WW) continue;
        acc += src[yy*WW + xx] * wf[c*9 + ky*3 + kx];
      }
    }
  }
  float a = ao[f];
  acc = acc >= 0.f ? acc : a*acc;
  offf[idx] = __float2bfloat16(acc);
}

// ---------------- K3: om = conv3x3(off_feat, W_om); mask channels pre-sigmoided ----------------
__global__ __launch_bounds__(256) void k_om(
    const bf16* __restrict__ offf, const float* __restrict__ Wom,
    const float* __restrict__ bom, float* __restrict__ om)
{
  int idx = blockIdx.x*256 + threadIdx.x;     // n*HW + p
  int p = idx & (HW-1);
  int n = idx >> 12;
  int h = p >> 6, w = p & 63;
  float acc[27];
  #pragma unroll
  for (int oc = 0; oc < 27; ++oc) acc[oc] = bom[oc];
  const bf16* fin = offf + (size_t)n*(FCH*HW);
  for (int c = 0; c < FCH; ++c) {
    const bf16* fc = fin + c*HW;
    #pragma unroll
    for (int ky = 0; ky < 3; ++ky) {
      int yy = h + ky - 1;
      if (yy < 0 || yy >= HH) continue;
      #pragma unroll
      for (int kx = 0; kx < 3; ++kx) {
        int xx = w + kx - 1;
        if (xx < 0 || xx >= WW) continue;
        float v = bf2f(fc[yy*WW + xx]);
        const float* wr = Wom + c*9 + ky*3 + kx;   // stride 576 over oc (uniform -> scalar loads)
        #pragma unroll
        for (int oc = 0; oc < 27; ++oc)
          acc[oc] += v * wr[oc*576];
      }
    }
  }
  float* op = om + (size_t)n*(27*HW) + p;
  #pragma unroll
  for (int oc = 0; oc < 18; ++oc) op[oc*HW] = acc[oc];
  #pragma unroll
  for (int oc = 18; oc < 27; ++oc) op[oc*HW] = 1.f/(1.f + __expf(-acc[oc]));
}

// ---------------- K4: modulated deformable conv ----------------
__global__ __launch_bounds__(256) void k_dcn(
    const bf16* __restrict__ feat, const float* __restrict__ om,
    const float* __restrict__ Wd, const float* __restrict__ bd,
    float* __restrict__ out)
{
  __shared__ bf16  sv[PX*SVS];      // interpolated, mask-modulated v[px][c*9+k]
  __shared__ int   spc[PX*9];       // packed clamped corner coords
  __shared__ float sww[PX*9*4];     // 4 corner weights (mask+validity folded)
  int t = threadIdx.x;
  int blk = blockIdx.x;
  int n = blk >> 7;                 // 128 blocks per image (4096/32)
  int pbase = (blk & 127) * PX;

  // Phase A: per (pixel, tap) bilinear parameters
  for (int e = t; e < PX*9; e += 256) {
    int px = e / 9, k = e - px*9;
    int p = pbase + px;
    int h = p >> 6, w = p & 63;
    const float* omn = om + (size_t)n*(27*HW) + p;
    float dy = omn[(2*k)*HW];
    float dx = omn[(2*k+1)*HW];
    float m  = omn[(18+k)*HW];      // already sigmoid
    float py = (float)(h + (k/3) - 1) + dy;
    float qx = (float)(w + (k%3) - 1) + dx;
    float y0f = floorf(py), x0f = floorf(qx);
    float wy = py - y0f, wx = qx - x0f;
    int y0 = (int)y0f, x0 = (int)x0f;
    int y1 = y0 + 1, x1 = x0 + 1;
    float w00 = (1.f-wy)*(1.f-wx)*m;
    float w01 = (1.f-wy)*wx*m;
    float w10 = wy*(1.f-wx)*m;
    float w11 = wy*wx*m;
    if (y0 < 0 || y0 >= HH) { w00 = 0.f; w01 = 0.f; }
    if (y1 < 0 || y1 >= HH) { w10 = 0.f; w11 = 0.f; }
    if (x0 < 0 || x0 >= WW) { w00 = 0.f; w10 = 0.f; }
    if (x1 < 0 || x1 >= WW) { w01 = 0.f; w11 = 0.f; }
    int y0c = min(max(y0,0),HH-1), y1c = min(max(y1,0),HH-1);
    int x0c = min(max(x0,0),WW-1), x1c = min(max(x1,0),WW-1);
    spc[e] = y0c | (y1c<<8) | (x0c<<16) | (x1c<<24);
    sww[e*4+0] = w00; sww[e*4+1] = w01; sww[e*4+2] = w10; sww[e*4+3] = w11;
  }
  __syncthreads();

  // Phase B: gather + bilinear interp into LDS (bf16)
  const bf16* fn = feat + (size_t)n*(FCH*HW);
  #pragma unroll 2
  for (int i = 0; i < (PX*576)/256; ++i) {    // 72 iters
    int e = t + i*256;
    int px = e / 576, kk = e - px*576;
    int c = kk / 9, k = kk - c*9;
    int te = px*9 + k;
    int pc = spc[te];
    int y0 = pc & 255, y1 = (pc>>8)&255, x0 = (pc>>16)&255, x1 = (pc>>24)&255;
    const float* wv = &sww[te*4];
    const bf16* fc = fn + c*HW;
    float v = wv[0]*bf2f(fc[y0*WW + x0]) + wv[1]*bf2f(fc[y0*WW + x1])
            + wv[2]*bf2f(fc[y1*WW + x0]) + wv[3]*bf2f(fc[y1*WW + x1]);
    sv[px*SVS + kk] = __float2bfloat16(v);
  }
  __syncthreads();

  // Phase C: out[oc, px] = sum_kk v[px][kk] * Wd[oc][kk]  (1px x 8oc per thread)
  int px  = t & (PX-1);
  int ocg = t >> 5;                 // 8 groups x 8 oc
  const bf16* svp = sv + px*SVS;
  const float* wbase = Wd + (size_t)ocg*8*576;
  float acc[8];
  #pragma unroll
  for (int j = 0; j < 8; ++j) acc[j] = 0.f;
  for (int kk = 0; kk < 576; kk += 8) {
    uint4 r = *(const uint4*)(svp + kk);      // 8 bf16, 16B-aligned
    float s0 = __uint_as_float(r.x << 16);
    float s1 = __uint_as_float(r.x & 0xffff0000u);
    float s2 = __uint_as_float(r.y << 16);
    float s3 = __uint_as_float(r.y & 0xffff0000u);
    float s4 = __uint_as_float(r.z << 16);
    float s5 = __uint_as_float(r.z & 0xffff0000u);
    float s6 = __uint_as_float(r.w << 16);
    float s7 = __uint_as_float(r.w & 0xffff0000u);
    #pragma unroll
    for (int j = 0; j < 8; ++j) {
      const float* wr = wbase + j*576 + kk;
      float4 wa = *(const float4*)(wr);
      float4 wb = *(const float4*)(wr + 4);
      acc[j] += s0*wa.x + s1*wa.y + s2*wa.z + s3*wa.w
              + s4*wb.x + s5*wb.y + s6*wb.z + s7*wb.w;
    }
  }
  int p = pbase + px;
  float* op = out + (size_t)n*(FCH*HW) + p;
  #pragma unroll
  for (int j = 0; j < 8; ++j)
    op[(ocg*8 + j)*HW] = acc[j] + bd[ocg*8 + j];
}

// ---------------- launcher ----------------
extern "C" void kernel_launch(void* const* d_in, const int* in_sizes, int n_in,
                              void* d_out, int out_size, void* d_ws, size_t ws_size,
                              hipStream_t stream)
{
  const float* x   = (const float*)d_in[0];
  // d_in[1] = flow (unused)
  const float* Wi  = (const float*)d_in[2];
  const float* bi  = (const float*)d_in[3];
  const float* ai  = (const float*)d_in[4];
  const float* Wo  = (const float*)d_in[5];
  const float* bo  = (const float*)d_in[6];
  const float* ao  = (const float*)d_in[7];
  const float* Wom = (const float*)d_in[8];
  const float* bom = (const float*)d_in[9];
  const float* Wd  = (const float*)d_in[10];
  const float* bd  = (const float*)d_in[11];
  float* out = (float*)d_out;

  // workspace: feat bf16 (20.97MB) | off_feat bf16 (20.97MB) | om f32 (17.69MB)
  bf16* feat = (bf16*)d_ws;
  bf16* offf = feat + (size_t)NIMG*FCH*HW;
  float* om  = (float*)(offf + (size_t)NIMG*FCH*HW);

  hipLaunchKernelGGL(k_feat,    dim3(NIMG*FCH*HW/256), dim3(256), 0, stream, x, Wi, bi, ai, feat);
  hipLaunchKernelGGL(k_offfeat, dim3(NIMG*FCH*HW/256), dim3(256), 0, stream, x, Wo, bo, ao, offf);
  hipLaunchKernelGGL(k_om,      dim3(NIMG*HW/256),     dim3(256), 0, stream, offf, Wom, bom, om);
  hipLaunchKernelGGL(k_dcn,     dim3(NIMG*HW/PX),      dim3(256), 0, stream, feat, om, Wd, bd, out);
}

// Round 2
// 1236.804 us; speedup vs baseline: 1.2539x; 1.2539x over previous
//
#include <hip/hip_runtime.h>
#include <hip/hip_bf16.h>
#include <hip/hip_fp16.h>
#include <stdint.h>

typedef __hip_bfloat16 bf16;
typedef __attribute__((ext_vector_type(8))) short short8v;
typedef __attribute__((ext_vector_type(4))) float f32x4;

#define NIMG 40      // B*T
#define TFR  5
#define CIN  3
#define FCH  64
#define HH   64
#define WW   64
#define HW   4096
#define PX   32      // pixels per block (half row)
#define SVS  584     // LDS row stride in bf16 (576 data + 8 pad; 1168B row, bank-spread)

__device__ __forceinline__ float bf2f(bf16 v){ return __bfloat162float(v); }

// ---------------- K0: permute+cast weights to bf16 [oc][k*64+c] ----------------
__global__ __launch_bounds__(256) void k_wprep(
    const float* __restrict__ Wd, const float* __restrict__ Wom,
    bf16* __restrict__ Wr_dcn, bf16* __restrict__ Wr_om)
{
  int idx = blockIdx.x*256 + threadIdx.x;   // 96*576 entries
  int kk = idx % 576; int oc = idx / 576;
  int k = kk >> 6, c = kk & 63;
  if (oc < 64) {
    Wr_dcn[idx] = __float2bfloat16(Wd[oc*576 + c*9 + k]);
  } else {
    int o2 = oc - 64;
    Wr_om[o2*576 + kk] = (o2 < 27) ? __float2bfloat16(Wom[o2*576 + c*9 + k])
                                   : __float2bfloat16(0.f);
  }
}

// ---------------- K1: feat = prelu(conv3x3(x, W_init))  [NHWC bf16 out] ----------------
__global__ __launch_bounds__(256) void k_feat(
    const float* __restrict__ x, const float* __restrict__ Wi,
    const float* __restrict__ bi, const float* __restrict__ ai,
    bf16* __restrict__ feat)
{
  int idx = blockIdx.x*256 + threadIdx.x;     // ((n*HW + p)*64 + f)
  int f = idx & 63;
  int p = (idx >> 6) & (HW-1);
  int n = idx >> 18;
  int h = p >> 6, w = p & 63;
  const float* xin = x + (size_t)n*(CIN*HW);
  const float* wf  = Wi + f*(CIN*9);
  float acc = bi[f];
  #pragma unroll
  for (int c = 0; c < CIN; ++c) {
    #pragma unroll
    for (int ky = 0; ky < 3; ++ky) {
      int yy = h + ky - 1;
      if (yy < 0 || yy >= HH) continue;
      #pragma unroll
      for (int kx = 0; kx < 3; ++kx) {
        int xx = w + kx - 1;
        if (xx < 0 || xx >= WW) continue;
        acc += xin[c*HW + yy*WW + xx] * wf[c*9 + ky*3 + kx];
      }
    }
  }
  float a = ai[f];
  acc = acc >= 0.f ? acc : a*acc;
  feat[idx] = __float2bfloat16(acc);
}

// ---------------- K2: off_feat = prelu(conv3x3(concat(ref0,x), W_off)) [NHWC bf16] ----------------
__global__ __launch_bounds__(256) void k_offfeat(
    const float* __restrict__ x, const float* __restrict__ Wo,
    const float* __restrict__ bo, const float* __restrict__ ao,
    bf16* __restrict__ offf)
{
  int idx = blockIdx.x*256 + threadIdx.x;
  int f = idx & 63;
  int p = (idx >> 6) & (HW-1);
  int n = idx >> 18;
  int h = p >> 6, w = p & 63;
  int n0 = (n/TFR)*TFR;                       // reference frame of this clip
  const float* xr = x + (size_t)n0*(CIN*HW);
  const float* xc = x + (size_t)n *(CIN*HW);
  const float* wf = Wo + f*(6*9);
  float acc = bo[f];
  #pragma unroll
  for (int c = 0; c < 6; ++c) {
    const float* src = (c < 3) ? (xr + c*HW) : (xc + (c-3)*HW);
    #pragma unroll
    for (int ky = 0; ky < 3; ++ky) {
      int yy = h + ky - 1;
      if (yy < 0 || yy >= HH) continue;
      #pragma unroll
      for (int kx = 0; kx < 3; ++kx) {
        int xx = w + kx - 1;
        if (xx < 0 || xx >= WW) continue;
        acc += src[yy*WW + xx] * wf[c*9 + ky*3 + kx];
      }
    }
  }
  float a = ao[f];
  acc = acc >= 0.f ? acc : a*acc;
  offf[idx] = __float2bfloat16(acc);
}

// ---------------- K3: om head via MFMA; writes planes 0..26 of out[n] ----------------
__global__ __launch_bounds__(256) void k_om(
    const bf16* __restrict__ offf, const bf16* __restrict__ Wr_om,
    const float* __restrict__ bom, float* om /* = d_out, [n][64][HW], planes 0..26 used */)
{
  __shared__ bf16 sp[PX*SVS];
  int t = threadIdx.x, blk = blockIdx.x;
  int n = blk >> 7, pbase = (blk & 127) * PX;
  int wv = t >> 6, lane = t & 63;

  // gather 3x3 patches: wave per (px,k), lane = channel (coalesced 128B loads)
  const bf16* fb = offf + (size_t)n*(HW*64);
  #pragma unroll 4
  for (int i = 0; i < 72; ++i) {
    int e = i*4 + wv;
    int px = e/9, k = e - px*9;
    int p = pbase + px;
    int h = p >> 6, w = p & 63;
    int y = h + k/3 - 1, xx = w + (k - (k/3)*3) - 1;
    bf16 v = __float2bfloat16(0.f);
    if (y >= 0 && y < HH && xx >= 0 && xx < WW) v = fb[((y<<6) + xx)*64 + lane];
    sp[px*SVS + k*64 + lane] = v;
  }
  __syncthreads();

  // MFMA: D[oc][px] = sum_kk Wom[oc][kk] * patch[px][kk]
  int mt = wv >> 1, nt = wv & 1;
  int row = lane & 15, ks = lane >> 4;
  f32x4 acc = {0.f, 0.f, 0.f, 0.f};
  const bf16* ap = Wr_om + (mt*16 + row)*576 + ks*8;
  const bf16* bp = sp + (nt*16 + row)*SVS + ks*8;
  for (int k0 = 0; k0 < 576; k0 += 32) {
    short8v a = *(const short8v*)(ap + k0);
    short8v b = *(const short8v*)(bp + k0);
    acc = __builtin_amdgcn_mfma_f32_16x16x32_bf16(a, b, acc, 0, 0, 0);
  }
  int p = pbase + nt*16 + row;
  float* op = om + (size_t)n*(64*HW) + p;
  #pragma unroll
  for (int j = 0; j < 4; ++j) {
    int oc = mt*16 + ks*4 + j;
    if (oc < 27) {
      float r = acc[j] + bom[oc];
      if (oc >= 18) r = 1.f/(1.f + __expf(-r));
      op[oc*HW] = r;
    }
  }
}

// ---------------- K4: modulated deformable conv (gather NHWC + MFMA) ----------------
__global__ __launch_bounds__(256) void k_dcn(
    const bf16* __restrict__ feat, const bf16* __restrict__ Wr,
    const float* __restrict__ bd, float* out /* aliases om planes 0..26 */)
{
  __shared__ bf16   sv[PX*SVS];     // v[px][k*64+c]
  __shared__ int    spc[PX*9];      // packed clamped corner coords
  __shared__ __half sww[PX*9*4];    // 4 corner weights (mask+validity folded)
  int t = threadIdx.x;
  int blk = blockIdx.x;
  int n = blk >> 7;
  int pbase = (blk & 127) * PX;
  const float* omn = out + (size_t)n*(64*HW);

  // Phase A: per (pixel, tap) bilinear parameters (reads om planes at OWN pixels only)
  for (int e = t; e < PX*9; e += 256) {
    int px = e / 9, k = e - px*9;
    int p = pbase + px;
    int h = p >> 6, w = p & 63;
    float dy = omn[(2*k)*HW + p];
    float dx = omn[(2*k+1)*HW + p];
    float m  = omn[(18+k)*HW + p];      // already sigmoid
    float py = (float)(h + (k/3) - 1) + dy;
    float qx = (float)(w + (k - (k/3)*3) - 1) + dx;
    float y0f = floorf(py), x0f = floorf(qx);
    float wy = py - y0f, wx = qx - x0f;
    int y0 = (int)y0f, x0 = (int)x0f;
    int y1 = y0 + 1, x1 = x0 + 1;
    float w00 = (1.f-wy)*(1.f-wx)*m;
    float w01 = (1.f-wy)*wx*m;
    float w10 = wy*(1.f-wx)*m;
    float w11 = wy*wx*m;
    if (y0 < 0 || y0 >= HH) { w00 = 0.f; w01 = 0.f; }
    if (y1 < 0 || y1 >= HH) { w10 = 0.f; w11 = 0.f; }
    if (x0 < 0 || x0 >= WW) { w00 = 0.f; w10 = 0.f; }
    if (x1 < 0 || x1 >= WW) { w01 = 0.f; w11 = 0.f; }
    int y0c = min(max(y0,0),HH-1), y1c = min(max(y1,0),HH-1);
    int x0c = min(max(x0,0),WW-1), x1c = min(max(x1,0),WW-1);
    spc[e] = y0c | (y1c<<8) | (x0c<<16) | (x1c<<24);
    sww[e*4+0] = __float2half(w00); sww[e*4+1] = __float2half(w01);
    sww[e*4+2] = __float2half(w10); sww[e*4+3] = __float2half(w11);
  }
  __syncthreads();

  // Phase B: coalesced bilinear gather; wave per (px,k), lane = channel
  const bf16* fb = feat + (size_t)n*(HW*64);
  int wv = t >> 6, lane = t & 63;
  #pragma unroll 4
  for (int i = 0; i < 72; ++i) {
    int e = i*4 + wv;
    int px = e/9, k = e - px*9;
    int pc = spc[e];
    int y0 = pc & 255, y1 = (pc>>8)&255, x0 = (pc>>16)&255, x1 = (pc>>24)&255;
    float w00 = __half2float(sww[e*4+0]);
    float w01 = __half2float(sww[e*4+1]);
    float w10 = __half2float(sww[e*4+2]);
    float w11 = __half2float(sww[e*4+3]);
    float v = w00*bf2f(fb[((y0<<6)+x0)*64 + lane]) + w01*bf2f(fb[((y0<<6)+x1)*64 + lane])
            + w10*bf2f(fb[((y1<<6)+x0)*64 + lane]) + w11*bf2f(fb[((y1<<6)+x1)*64 + lane]);
    sv[px*SVS + k*64 + lane] = __float2bfloat16(v);
  }
  __syncthreads();

  // Phase C: MFMA  D[oc][px] = sum_kk Wd[oc][kk] * v[px][kk]
  int nt = wv & 1, mt0 = wv >> 1;          // wave -> (px-tile, two oc-tiles)
  int row = lane & 15, ks = lane >> 4;
  f32x4 acc0 = {0.f,0.f,0.f,0.f}, acc1 = {0.f,0.f,0.f,0.f};
  const bf16* a0p = Wr + (mt0*16 + row)*576 + ks*8;
  const bf16* a1p = Wr + ((mt0+2)*16 + row)*576 + ks*8;
  const bf16* bp  = sv + (nt*16 + row)*SVS + ks*8;
  for (int k0 = 0; k0 < 576; k0 += 32) {
    short8v a0 = *(const short8v*)(a0p + k0);
    short8v a1 = *(const short8v*)(a1p + k0);
    short8v b  = *(const short8v*)(bp + k0);
    acc0 = __builtin_amdgcn_mfma_f32_16x16x32_bf16(a0, b, acc0, 0, 0, 0);
    acc1 = __builtin_amdgcn_mfma_f32_16x16x32_bf16(a1, b, acc1, 0, 0, 0);
  }
  int p = pbase + nt*16 + row;
  float* op = out + (size_t)n*(64*HW) + p;
  #pragma unroll
  for (int j = 0; j < 4; ++j) {
    int oc0 = mt0*16 + ks*4 + j;
    int oc1 = (mt0+2)*16 + ks*4 + j;
    op[oc0*HW] = acc0[j] + bd[oc0];
    op[oc1*HW] = acc1[j] + bd[oc1];
  }
}

// ---------------- launcher ----------------
extern "C" void kernel_launch(void* const* d_in, const int* in_sizes, int n_in,
                              void* d_out, int out_size, void* d_ws, size_t ws_size,
                              hipStream_t stream)
{
  const float* x   = (const float*)d_in[0];
  // d_in[1] = flow (unused)
  const float* Wi  = (const float*)d_in[2];
  const float* bi  = (const float*)d_in[3];
  const float* ai  = (const float*)d_in[4];
  const float* Wo  = (const float*)d_in[5];
  const float* bo  = (const float*)d_in[6];
  const float* ao  = (const float*)d_in[7];
  const float* Wom = (const float*)d_in[8];
  const float* bom = (const float*)d_in[9];
  const float* Wd  = (const float*)d_in[10];
  const float* bd  = (const float*)d_in[11];
  float* out = (float*)d_out;

  // workspace: feat NHWC bf16 | off_feat NHWC bf16 | Wr_dcn | Wr_om   (~42.1 MB)
  bf16* feat   = (bf16*)d_ws;
  bf16* offf   = feat + (size_t)NIMG*HW*64;
  bf16* Wr_dcn = offf + (size_t)NIMG*HW*64;
  bf16* Wr_om  = Wr_dcn + 64*576;
  // om planes live in d_out: first 27 channel-planes of each image's [64][HW] slice.

  hipLaunchKernelGGL(k_wprep,   dim3(96*576/256),      dim3(256), 0, stream, Wd, Wom, Wr_dcn, Wr_om);
  hipLaunchKernelGGL(k_feat,    dim3(NIMG*HW*64/256),  dim3(256), 0, stream, x, Wi, bi, ai, feat);
  hipLaunchKernelGGL(k_offfeat, dim3(NIMG*HW*64/256),  dim3(256), 0, stream, x, Wo, bo, ao, offf);
  hipLaunchKernelGGL(k_om,      dim3(NIMG*HW/PX),      dim3(256), 0, stream, offf, Wr_om, bom, out);
  hipLaunchKernelGGL(k_dcn,     dim3(NIMG*HW/PX),      dim3(256), 0, stream, feat, Wr_dcn, bd, out);
}

// Round 3
// 373.070 us; speedup vs baseline: 4.1571x; 3.3152x over previous
//
#include <hip/hip_runtime.h>
#include <hip/hip_bf16.h>
#include <hip/hip_fp16.h>
#include <stdint.h>

typedef __hip_bfloat16 bf16;
typedef __attribute__((ext_vector_type(8))) short short8v;
typedef __attribute__((ext_vector_type(4))) float f32x4;

#define NIMG 40      // B*T
#define TFR  5
#define CIN  3
#define FCH  64
#define HH   64
#define WW   64
#define HW   4096
#define PX   32      // pixels per block (half row)
#define SVS  584     // LDS row stride in bf16 for 576-wide tiles
#define PPS  72      // LDS row stride for 64-wide front patch

__device__ __forceinline__ float bf2f(bf16 v){ return __bfloat162float(v); }

// ---------------- K0: weight prep ----------------
// Wr_dcn[64][576]  kk = k*64+c          <- Wd[oc][c][k]
// Wr_om [32][576]  kk = k*64+c          <- Wom[oc][c][k] (rows 27..31 zero)
// Wr_f  [64][64]   kk = c*9+k (cur)     <- Wi[f][c][k]   (kk 27..63 zero)
// Wr_o  [64][64]   kk 0..26 cur, 27..53 ref <- Wo reordered (54..63 zero)
__global__ __launch_bounds__(256) void k_wprep(
    const float* __restrict__ Wd, const float* __restrict__ Wom,
    const float* __restrict__ Wi, const float* __restrict__ Wo,
    bf16* __restrict__ Wr_dcn, bf16* __restrict__ Wr_om,
    bf16* __restrict__ Wr_f, bf16* __restrict__ Wr_o)
{
  int idx = blockIdx.x*256 + threadIdx.x;
  if (idx < 36864) {                         // dcn
    int kk = idx % 576, oc = idx / 576;
    int k = kk >> 6, c = kk & 63;
    Wr_dcn[idx] = __float2bfloat16(Wd[oc*576 + c*9 + k]);
  } else if (idx < 36864 + 18432) {          // om
    int q = idx - 36864;
    int kk = q % 576, oc = q / 576;
    int k = kk >> 6, c = kk & 63;
    Wr_om[q] = (oc < 27) ? __float2bfloat16(Wom[oc*576 + c*9 + k])
                         : __float2bfloat16(0.f);
  } else if (idx < 36864 + 18432 + 4096) {   // front feat
    int q = idx - 36864 - 18432;
    int kk = q & 63, f = q >> 6;
    Wr_f[q] = (kk < 27) ? __float2bfloat16(Wi[f*27 + kk])
                        : __float2bfloat16(0.f);
  } else if (idx < 36864 + 18432 + 8192) {   // front off
    int q = idx - 36864 - 18432 - 4096;
    int kk = q & 63, f = q >> 6;
    float v = 0.f;
    if (kk < 27)       v = Wo[f*54 + 27 + kk];    // cur channels (concat idx 3..5)
    else if (kk < 54)  v = Wo[f*54 + (kk - 27)];  // ref channels (concat idx 0..2)
    Wr_o[q] = __float2bfloat16(v);
  }
}

// ---------------- K1: fused feat + off_feat via MFMA [NHWC bf16 out] ----------------
__global__ __launch_bounds__(256) void k_front(
    const float* __restrict__ x,
    const bf16* __restrict__ Wr_f, const bf16* __restrict__ Wr_o,
    const float* __restrict__ bi, const float* __restrict__ ai,
    const float* __restrict__ bo, const float* __restrict__ aof,
    bf16* __restrict__ feat, bf16* __restrict__ offf)
{
  __shared__ bf16 sp[PX*PPS];
  int t = threadIdx.x, blk = blockIdx.x;
  int n = blk >> 7;
  int pbase = (blk & 127) * PX;
  int h = pbase >> 6;
  int wbase = pbase & 63;
  int n0 = (n/TFR)*TFR;
  const float* xc = x + (size_t)n*(CIN*HW);
  const float* xr = x + (size_t)n0*(CIN*HW);

  // im2col patch [32 px][64 kk]: kk 0..26 cur (c*9+k), 27..53 ref, 54..63 zero
  #pragma unroll
  for (int i = 0; i < 8; ++i) {
    int e = i*256 + t;
    int kk = e >> 5, px = e & 31;
    float v = 0.f;
    if (kk < 54) {
      int cur = (kk < 27);
      int kb = cur ? kk : kk - 27;
      int c = kb / 9, k = kb - c*9;
      int y  = h + k/3 - 1;
      int xx = wbase + px + (k - (k/3)*3) - 1;
      if (y >= 0 && y < HH && xx >= 0 && xx < WW)
        v = (cur ? xc : xr)[c*HW + y*WW + xx];
    }
    sp[px*PPS + kk] = __float2bfloat16(v);
  }
  __syncthreads();

  int wv = t >> 6, lane = t & 63;
  int row = lane & 15, ks = lane >> 4;
  const bf16* af = Wr_f + (wv*16 + row)*64 + ks*8;
  const bf16* aw = Wr_o + (wv*16 + row)*64 + ks*8;
  short8v af0 = *(const short8v*)(af);
  short8v aw0 = *(const short8v*)(aw);
  short8v aw1 = *(const short8v*)(aw + 32);
  #pragma unroll
  for (int nt = 0; nt < 2; ++nt) {
    const bf16* bp = sp + (nt*16 + row)*PPS + ks*8;
    short8v b0 = *(const short8v*)(bp);
    short8v b1 = *(const short8v*)(bp + 32);
    f32x4 accf = {0.f,0.f,0.f,0.f}, acco = {0.f,0.f,0.f,0.f};
    accf = __builtin_amdgcn_mfma_f32_16x16x32_bf16(af0, b0, accf, 0, 0, 0);
    acco = __builtin_amdgcn_mfma_f32_16x16x32_bf16(aw0, b0, acco, 0, 0, 0);
    acco = __builtin_amdgcn_mfma_f32_16x16x32_bf16(aw1, b1, acco, 0, 0, 0);
    int p  = pbase + nt*16 + row;
    int f0 = wv*16 + ks*4;
    size_t base = ((size_t)n*HW + p)*64 + f0;
    union { ushort4 u; bf16 b[4]; } pf, po;
    #pragma unroll
    for (int j = 0; j < 4; ++j) {
      float vf = accf[j] + bi[f0+j];
      float aF = ai[f0+j];
      vf = vf >= 0.f ? vf : aF*vf;
      pf.b[j] = __float2bfloat16(vf);
      float vo = acco[j] + bo[f0+j];
      float aO = aof[f0+j];
      vo = vo >= 0.f ? vo : aO*vo;
      po.b[j] = __float2bfloat16(vo);
    }
    *(ushort4*)(feat + base) = pf.u;
    *(ushort4*)(offf + base) = po.u;
  }
}

// ---------------- K3: om head via MFMA; writes planes 0..26 of out[n] ----------------
__global__ __launch_bounds__(256) void k_om(
    const bf16* __restrict__ offf, const bf16* __restrict__ Wr_om,
    const float* __restrict__ bom, float* om /* = d_out, [n][64][HW], planes 0..26 used */)
{
  __shared__ bf16 sp[PX*SVS];
  int t = threadIdx.x, blk = blockIdx.x;
  int n = blk >> 7, pbase = (blk & 127) * PX;
  int wv = t >> 6, lane = t & 63;

  // gather 3x3 patches: wave per (px,k), lane = channel (coalesced 128B loads)
  const bf16* fb = offf + (size_t)n*(HW*64);
  #pragma unroll 4
  for (int i = 0; i < 72; ++i) {
    int e = i*4 + wv;
    int px = e/9, k = e - px*9;
    int p = pbase + px;
    int h = p >> 6, w = p & 63;
    int y = h + k/3 - 1, xx = w + (k - (k/3)*3) - 1;
    bf16 v = __float2bfloat16(0.f);
    if (y >= 0 && y < HH && xx >= 0 && xx < WW) v = fb[((y<<6) + xx)*64 + lane];
    sp[px*SVS + k*64 + lane] = v;
  }
  __syncthreads();

  // MFMA: D[oc][px] = sum_kk Wom[oc][kk] * patch[px][kk]
  int mt = wv >> 1, nt = wv & 1;
  int row = lane & 15, ks = lane >> 4;
  f32x4 acc = {0.f, 0.f, 0.f, 0.f};
  const bf16* ap = Wr_om + (mt*16 + row)*576 + ks*8;
  const bf16* bp = sp + (nt*16 + row)*SVS + ks*8;
  for (int k0 = 0; k0 < 576; k0 += 32) {
    short8v a = *(const short8v*)(ap + k0);
    short8v b = *(const short8v*)(bp + k0);
    acc = __builtin_amdgcn_mfma_f32_16x16x32_bf16(a, b, acc, 0, 0, 0);
  }
  int p = pbase + nt*16 + row;
  float* op = om + (size_t)n*(64*HW) + p;
  #pragma unroll
  for (int j = 0; j < 4; ++j) {
    int oc = mt*16 + ks*4 + j;
    if (oc < 27) {
      float r = acc[j] + bom[oc];
      if (oc >= 18) r = 1.f/(1.f + __expf(-r));
      op[oc*HW] = r;
    }
  }
}

// ---------------- K4: modulated deformable conv (gather NHWC + MFMA) ----------------
__global__ __launch_bounds__(256) void k_dcn(
    const bf16* __restrict__ feat, const bf16* __restrict__ Wr,
    const float* __restrict__ bd, float* out /* aliases om planes 0..26 */)
{
  __shared__ bf16   sv[PX*SVS];     // v[px][k*64+c]
  __shared__ int    spc[PX*9];      // packed clamped corner coords
  __shared__ __half sww[PX*9*4];    // 4 corner weights (mask+validity folded)
  int t = threadIdx.x;
  int blk = blockIdx.x;
  int n = blk >> 7;
  int pbase = (blk & 127) * PX;
  const float* omn = out + (size_t)n*(64*HW);

  // Phase A: per (pixel, tap) bilinear parameters (reads om planes at OWN pixels only)
  for (int e = t; e < PX*9; e += 256) {
    int px = e / 9, k = e - px*9;
    int p = pbase + px;
    int h = p >> 6, w = p & 63;
    float dy = omn[(2*k)*HW + p];
    float dx = omn[(2*k+1)*HW + p];
    float m  = omn[(18+k)*HW + p];      // already sigmoid
    float py = (float)(h + (k/3) - 1) + dy;
    float qx = (float)(w + (k - (k/3)*3) - 1) + dx;
    float y0f = floorf(py), x0f = floorf(qx);
    float wy = py - y0f, wx = qx - x0f;
    int y0 = (int)y0f, x0 = (int)x0f;
    int y1 = y0 + 1, x1 = x0 + 1;
    float w00 = (1.f-wy)*(1.f-wx)*m;
    float w01 = (1.f-wy)*wx*m;
    float w10 = wy*(1.f-wx)*m;
    float w11 = wy*wx*m;
    if (y0 < 0 || y0 >= HH) { w00 = 0.f; w01 = 0.f; }
    if (y1 < 0 || y1 >= HH) { w10 = 0.f; w11 = 0.f; }
    if (x0 < 0 || x0 >= WW) { w00 = 0.f; w10 = 0.f; }
    if (x1 < 0 || x1 >= WW) { w01 = 0.f; w11 = 0.f; }
    int y0c = min(max(y0,0),HH-1), y1c = min(max(y1,0),HH-1);
    int x0c = min(max(x0,0),WW-1), x1c = min(max(x1,0),WW-1);
    spc[e] = y0c | (y1c<<8) | (x0c<<16) | (x1c<<24);
    sww[e*4+0] = __float2half(w00); sww[e*4+1] = __float2half(w01);
    sww[e*4+2] = __float2half(w10); sww[e*4+3] = __float2half(w11);
  }
  __syncthreads();

  // Phase B: coalesced bilinear gather; wave per (px,k), lane = channel
  const bf16* fb = feat + (size_t)n*(HW*64);
  int wv = t >> 6, lane = t & 63;
  #pragma unroll 4
  for (int i = 0; i < 72; ++i) {
    int e = i*4 + wv;
    int px = e/9, k = e - px*9;
    int pc = spc[e];
    int y0 = pc & 255, y1 = (pc>>8)&255, x0 = (pc>>16)&255, x1 = (pc>>24)&255;
    float w00 = __half2float(sww[e*4+0]);
    float w01 = __half2float(sww[e*4+1]);
    float w10 = __half2float(sww[e*4+2]);
    float w11 = __half2float(sww[e*4+3]);
    float v = w00*bf2f(fb[((y0<<6)+x0)*64 + lane]) + w01*bf2f(fb[((y0<<6)+x1)*64 + lane])
            + w10*bf2f(fb[((y1<<6)+x0)*64 + lane]) + w11*bf2f(fb[((y1<<6)+x1)*64 + lane]);
    sv[px*SVS + k*64 + lane] = __float2bfloat16(v);
  }
  __syncthreads();

  // Phase C: MFMA  D[oc][px] = sum_kk Wd[oc][kk] * v[px][kk]
  int nt = wv & 1, mt0 = wv >> 1;          // wave -> (px-tile, two oc-tiles)
  int row = lane & 15, ks = lane >> 4;
  f32x4 acc0 = {0.f,0.f,0.f,0.f}, acc1 = {0.f,0.f,0.f,0.f};
  const bf16* a0p = Wr + (mt0*16 + row)*576 + ks*8;
  const bf16* a1p = Wr + ((mt0+2)*16 + row)*576 + ks*8;
  const bf16* bp  = sv + (nt*16 + row)*SVS + ks*8;
  for (int k0 = 0; k0 < 576; k0 += 32) {
    short8v a0 = *(const short8v*)(a0p + k0);
    short8v a1 = *(const short8v*)(a1p + k0);
    short8v b  = *(const short8v*)(bp + k0);
    acc0 = __builtin_amdgcn_mfma_f32_16x16x32_bf16(a0, b, acc0, 0, 0, 0);
    acc1 = __builtin_amdgcn_mfma_f32_16x16x32_bf16(a1, b, acc1, 0, 0, 0);
  }
  int p = pbase + nt*16 + row;
  float* op = out + (size_t)n*(64*HW) + p;
  #pragma unroll
  for (int j = 0; j < 4; ++j) {
    int oc0 = mt0*16 + ks*4 + j;
    int oc1 = (mt0+2)*16 + ks*4 + j;
    op[oc0*HW] = acc0[j] + bd[oc0];
    op[oc1*HW] = acc1[j] + bd[oc1];
  }
}

// ---------------- launcher ----------------
extern "C" void kernel_launch(void* const* d_in, const int* in_sizes, int n_in,
                              void* d_out, int out_size, void* d_ws, size_t ws_size,
                              hipStream_t stream)
{
  const float* x   = (const float*)d_in[0];
  // d_in[1] = flow (unused)
  const float* Wi  = (const float*)d_in[2];
  const float* bi  = (const float*)d_in[3];
  const float* ai  = (const float*)d_in[4];
  const float* Wo  = (const float*)d_in[5];
  const float* bo  = (const float*)d_in[6];
  const float* aof = (const float*)d_in[7];
  const float* Wom = (const float*)d_in[8];
  const float* bom = (const float*)d_in[9];
  const float* Wd  = (const float*)d_in[10];
  const float* bd  = (const float*)d_in[11];
  float* out = (float*)d_out;

  // workspace: feat NHWC bf16 | off_feat NHWC bf16 | Wr_dcn | Wr_om | Wr_f | Wr_o
  bf16* feat   = (bf16*)d_ws;
  bf16* offf   = feat + (size_t)NIMG*HW*64;
  bf16* Wr_dcn = offf + (size_t)NIMG*HW*64;
  bf16* Wr_om  = Wr_dcn + 64*576;
  bf16* Wr_f   = Wr_om + 32*576;
  bf16* Wr_o   = Wr_f + 64*64;
  // om planes live in d_out: first 27 channel-planes of each image's [64][HW] slice.

  hipLaunchKernelGGL(k_wprep, dim3(248),         dim3(256), 0, stream,
                     Wd, Wom, Wi, Wo, Wr_dcn, Wr_om, Wr_f, Wr_o);
  hipLaunchKernelGGL(k_front, dim3(NIMG*HW/PX),  dim3(256), 0, stream,
                     x, Wr_f, Wr_o, bi, ai, bo, aof, feat, offf);
  hipLaunchKernelGGL(k_om,    dim3(NIMG*HW/PX),  dim3(256), 0, stream, offf, Wr_om, bom, out);
  hipLaunchKernelGGL(k_dcn,   dim3(NIMG*HW/PX),  dim3(256), 0, stream, feat, Wr_dcn, bd, out);
}

// Round 4
// 264.830 us; speedup vs baseline: 5.8562x; 1.4087x over previous
//
#include <hip/hip_runtime.h>
#include <hip/hip_bf16.h>
#include <hip/hip_fp16.h>
#include <stdint.h>

typedef _Float16 h16;
typedef __attribute__((ext_vector_type(8))) _Float16 f16x8;
typedef __attribute__((ext_vector_type(4))) float f32x4;

#define NIMG 40      // B*T
#define TFR  5
#define CIN  3
#define FCH  64
#define HH   64
#define WW   64
#define HW   4096
#define PX   32      // pixels per block (half row)
#define SVS  584     // LDS row stride in halves for 576-wide tiles (pad vs bank conflicts)
#define PPS  72      // LDS row stride for 64-wide front patch

union U32H2 { uint u; __half2 h; };

// ---------------- K0: weight prep (fp16) ----------------
// Wr_dcn[64][576]  kk = k*64+c          <- Wd[oc][c][k]
// Wr_om [32][576]  kk = k*64+c          <- Wom[oc][c][k] (rows 27..31 zero)
// Wr_f  [64][64]   kk = c*9+k (cur)     <- Wi[f][c][k]   (kk 27..63 zero)
// Wr_o  [64][64]   kk 0..26 cur, 27..53 ref <- Wo reordered (54..63 zero)
__global__ __launch_bounds__(256) void k_wprep(
    const float* __restrict__ Wd, const float* __restrict__ Wom,
    const float* __restrict__ Wi, const float* __restrict__ Wo,
    __half* __restrict__ Wr_dcn, __half* __restrict__ Wr_om,
    __half* __restrict__ Wr_f, __half* __restrict__ Wr_o)
{
  int idx = blockIdx.x*256 + threadIdx.x;
  if (idx < 36864) {                         // dcn
    int kk = idx % 576, oc = idx / 576;
    int k = kk >> 6, c = kk & 63;
    Wr_dcn[idx] = __float2half(Wd[oc*576 + c*9 + k]);
  } else if (idx < 36864 + 18432) {          // om
    int q = idx - 36864;
    int kk = q % 576, oc = q / 576;
    int k = kk >> 6, c = kk & 63;
    Wr_om[q] = (oc < 27) ? __float2half(Wom[oc*576 + c*9 + k]) : __float2half(0.f);
  } else if (idx < 36864 + 18432 + 4096) {   // front feat
    int q = idx - 36864 - 18432;
    int kk = q & 63, f = q >> 6;
    Wr_f[q] = (kk < 27) ? __float2half(Wi[f*27 + kk]) : __float2half(0.f);
  } else if (idx < 36864 + 18432 + 8192) {   // front off
    int q = idx - 36864 - 18432 - 4096;
    int kk = q & 63, f = q >> 6;
    float v = 0.f;
    if (kk < 27)       v = Wo[f*54 + 27 + kk];    // cur channels (concat idx 3..5)
    else if (kk < 54)  v = Wo[f*54 + (kk - 27)];  // ref channels (concat idx 0..2)
    Wr_o[q] = __float2half(v);
  }
}

// ---------------- K1: fused feat + off_feat via MFMA [NHWC fp16 out] ----------------
__global__ __launch_bounds__(256) void k_front(
    const float* __restrict__ x,
    const __half* __restrict__ Wr_f, const __half* __restrict__ Wr_o,
    const float* __restrict__ bi, const float* __restrict__ ai,
    const float* __restrict__ bo, const float* __restrict__ aof,
    __half* __restrict__ feat, __half* __restrict__ offf)
{
  __shared__ __align__(16) __half sp[PX*PPS];
  int t = threadIdx.x, blk = blockIdx.x;
  int n = blk >> 7;
  int pbase = (blk & 127) * PX;
  int h = pbase >> 6;
  int wbase = pbase & 63;
  int n0 = (n/TFR)*TFR;
  const float* xc = x + (size_t)n*(CIN*HW);
  const float* xr = x + (size_t)n0*(CIN*HW);

  // im2col patch [32 px][64 kk]: kk 0..26 cur (c*9+k), 27..53 ref, 54..63 zero
  #pragma unroll
  for (int i = 0; i < 8; ++i) {
    int e = i*256 + t;
    int kk = e >> 5, px = e & 31;
    float v = 0.f;
    if (kk < 54) {
      int cur = (kk < 27);
      int kb = cur ? kk : kk - 27;
      int c = kb / 9, k = kb - c*9;
      int y  = h + k/3 - 1;
      int xx = wbase + px + (k - (k/3)*3) - 1;
      if (y >= 0 && y < HH && xx >= 0 && xx < WW)
        v = (cur ? xc : xr)[c*HW + y*WW + xx];
    }
    sp[px*PPS + kk] = __float2half(v);
  }
  __syncthreads();

  int wv = t >> 6, lane = t & 63;
  int row = lane & 15, ks = lane >> 4;
  const __half* af = Wr_f + (wv*16 + row)*64 + ks*8;
  const __half* aw = Wr_o + (wv*16 + row)*64 + ks*8;
  f16x8 af0 = *(const f16x8*)(af);
  f16x8 aw0 = *(const f16x8*)(aw);
  f16x8 aw1 = *(const f16x8*)(aw + 32);
  #pragma unroll
  for (int nt = 0; nt < 2; ++nt) {
    const __half* bp = sp + (nt*16 + row)*PPS + ks*8;
    f16x8 b0 = *(const f16x8*)(bp);
    f16x8 b1 = *(const f16x8*)(bp + 32);
    f32x4 accf = {0.f,0.f,0.f,0.f}, acco = {0.f,0.f,0.f,0.f};
    accf = __builtin_amdgcn_mfma_f32_16x16x32_f16(af0, b0, accf, 0, 0, 0);
    acco = __builtin_amdgcn_mfma_f32_16x16x32_f16(aw0, b0, acco, 0, 0, 0);
    acco = __builtin_amdgcn_mfma_f32_16x16x32_f16(aw1, b1, acco, 0, 0, 0);
    int p  = pbase + nt*16 + row;
    int f0 = wv*16 + ks*4;
    size_t base = ((size_t)n*HW + p)*64 + f0;
    union { ushort4 u; __half b[4]; } pf, po;
    #pragma unroll
    for (int j = 0; j < 4; ++j) {
      float vf = accf[j] + bi[f0+j];
      float aF = ai[f0+j];
      vf = vf >= 0.f ? vf : aF*vf;
      pf.b[j] = __float2half(vf);
      float vo = acco[j] + bo[f0+j];
      float aO = aof[f0+j];
      vo = vo >= 0.f ? vo : aO*vo;
      po.b[j] = __float2half(vo);
    }
    *(ushort4*)(feat + base) = pf.u;
    *(ushort4*)(offf + base) = po.u;
  }
}

// ---------------- K3: om head via MFMA; writes planes 0..26 of out[n] ----------------
__global__ __launch_bounds__(256) void k_om(
    const __half* __restrict__ offf, const __half* __restrict__ Wr_om,
    const float* __restrict__ bom, float* om /* = d_out, [n][64][HW], planes 0..26 used */)
{
  __shared__ __align__(16) __half sp[PX*SVS];
  int t = threadIdx.x, blk = blockIdx.x;
  int n = blk >> 7, pbase = (blk & 127) * PX;
  int wv = t >> 6, lane = t & 63;
  int hi = lane >> 5, l2 = lane & 31;

  // gather 3x3 patches: half-wave per (px,k), lane-pair = 2 channels (uint loads)
  const char* fb = (const char*)(offf + (size_t)n*(HW*64));
  #pragma unroll 4
  for (int i = 0; i < 36; ++i) {
    int e = i*8 + wv*2 + hi;
    int px = e/9, k = e - px*9;
    int p = pbase + px;
    int h = p >> 6, w = p & 63;
    int y = h + k/3 - 1, xx = w + (k - (k/3)*3) - 1;
    uint v = 0u;
    if (y >= 0 && y < HH && xx >= 0 && xx < WW)
      v = *(const uint*)(fb + (((y<<6) + xx)<<7) + l2*4);
    *(uint*)((char*)sp + (px*SVS + k*64)*2 + l2*4) = v;
  }
  __syncthreads();

  // MFMA: D[oc][px] = sum_kk Wom[oc][kk] * patch[px][kk]
  int mt = wv >> 1, nt = wv & 1;
  int row = lane & 15, ks = lane >> 4;
  f32x4 acc = {0.f, 0.f, 0.f, 0.f};
  const __half* ap = Wr_om + (mt*16 + row)*576 + ks*8;
  const __half* bp = sp + (nt*16 + row)*SVS + ks*8;
  for (int k0 = 0; k0 < 576; k0 += 32) {
    f16x8 a = *(const f16x8*)(ap + k0);
    f16x8 b = *(const f16x8*)(bp + k0);
    acc = __builtin_amdgcn_mfma_f32_16x16x32_f16(a, b, acc, 0, 0, 0);
  }
  int p = pbase + nt*16 + row;
  float* op = om + (size_t)n*(64*HW) + p;
  #pragma unroll
  for (int j = 0; j < 4; ++j) {
    int oc = mt*16 + ks*4 + j;
    if (oc < 27) {
      float r = acc[j] + bom[oc];
      if (oc >= 18) r = 1.f/(1.f + __expf(-r));
      op[oc*HW] = r;
    }
  }
}

// ---------------- K4: modulated deformable conv (packed-fp16 gather + MFMA) ----------------
__global__ __launch_bounds__(256) void k_dcn(
    const __half* __restrict__ feat, const __half* __restrict__ Wr,
    const float* __restrict__ bd, float* out /* aliases om planes 0..26 */)
{
  __shared__ __align__(16) __half sv[PX*SVS];   // v[px][k*64+c]
  __shared__ __align__(16) int4  soff[PX*9];    // 4 corner byte offsets into feat[n]
  __shared__ __align__(16) uint4 swgt[PX*9];    // 4 corner weights as broadcast half2
  __shared__ int sdso[PX*9];                    // LDS dest byte offset per tap
  int t = threadIdx.x;
  int blk = blockIdx.x;
  int n = blk >> 7;
  int pbase = (blk & 127) * PX;
  const float* omn = out + (size_t)n*(64*HW);

  // Phase A: per (pixel, tap) bilinear parameters (reads om planes at OWN pixels only)
  for (int e = t; e < PX*9; e += 256) {
    int px = e / 9, k = e - px*9;
    int p = pbase + px;
    int h = p >> 6, w = p & 63;
    float dy = omn[(2*k)*HW + p];
    float dx = omn[(2*k+1)*HW + p];
    float m  = omn[(18+k)*HW + p];      // already sigmoid
    float py = (float)(h + (k/3) - 1) + dy;
    float qx = (float)(w + (k - (k/3)*3) - 1) + dx;
    float y0f = floorf(py), x0f = floorf(qx);
    float wy = py - y0f, wx = qx - x0f;
    int y0 = (int)y0f, x0 = (int)x0f;
    int y1 = y0 + 1, x1 = x0 + 1;
    float w00 = (1.f-wy)*(1.f-wx)*m;
    float w01 = (1.f-wy)*wx*m;
    float w10 = wy*(1.f-wx)*m;
    float w11 = wy*wx*m;
    if (y0 < 0 || y0 >= HH) { w00 = 0.f; w01 = 0.f; }
    if (y1 < 0 || y1 >= HH) { w10 = 0.f; w11 = 0.f; }
    if (x0 < 0 || x0 >= WW) { w00 = 0.f; w10 = 0.f; }
    if (x1 < 0 || x1 >= WW) { w01 = 0.f; w11 = 0.f; }
    int y0c = min(max(y0,0),HH-1), y1c = min(max(y1,0),HH-1);
    int x0c = min(max(x0,0),WW-1), x1c = min(max(x1,0),WW-1);
    soff[e] = make_int4((((y0c<<6)+x0c)<<7), (((y0c<<6)+x1c)<<7),
                        (((y1c<<6)+x0c)<<7), (((y1c<<6)+x1c)<<7));
    U32H2 u00, u01, u10, u11;
    u00.h = __float2half2_rn(w00); u01.h = __float2half2_rn(w01);
    u10.h = __float2half2_rn(w10); u11.h = __float2half2_rn(w11);
    swgt[e] = make_uint4(u00.u, u01.u, u10.u, u11.u);
    sdso[e] = (px*SVS + k*64)*2;
  }
  __syncthreads();

  // Phase B: packed bilinear gather; half-wave per (px,k), lane-pair = 2 channels
  const char* fb = (const char*)(feat + (size_t)n*(HW*64));
  int wv = t >> 6, lane = t & 63;
  int hi = lane >> 5, l2 = lane & 31;
  int lo4 = l2*4;
  #pragma unroll 4
  for (int i = 0; i < 36; ++i) {
    int e = i*8 + wv*2 + hi;
    int4  off = soff[e];
    uint4 wq  = swgt[e];
    int   dso = sdso[e];
    U32H2 c00, c01, c10, c11, W00, W01, W10, W11, r;
    c00.u = *(const uint*)(fb + off.x + lo4);
    c01.u = *(const uint*)(fb + off.y + lo4);
    c10.u = *(const uint*)(fb + off.z + lo4);
    c11.u = *(const uint*)(fb + off.w + lo4);
    W00.u = wq.x; W01.u = wq.y; W10.u = wq.z; W11.u = wq.w;
    __half2 v = __hmul2(W00.h, c00.h);
    v = __hfma2(W01.h, c01.h, v);
    v = __hfma2(W10.h, c10.h, v);
    v = __hfma2(W11.h, c11.h, v);
    r.h = v;
    *(uint*)((char*)sv + dso + lo4) = r.u;
  }
  __syncthreads();

  // Phase C: MFMA  D[oc][px] = sum_kk Wd[oc][kk] * v[px][kk]
  int nt = wv & 1, mt0 = wv >> 1;          // wave -> (px-tile, two oc-tiles)
  int row = lane & 15, ks = lane >> 4;
  f32x4 acc0 = {0.f,0.f,0.f,0.f}, acc1 = {0.f,0.f,0.f,0.f};
  const __half* a0p = Wr + (mt0*16 + row)*576 + ks*8;
  const __half* a1p = Wr + ((mt0+2)*16 + row)*576 + ks*8;
  const __half* bp  = sv + (nt*16 + row)*SVS + ks*8;
  for (int k0 = 0; k0 < 576; k0 += 32) {
    f16x8 a0 = *(const f16x8*)(a0p + k0);
    f16x8 a1 = *(const f16x8*)(a1p + k0);
    f16x8 b  = *(const f16x8*)(bp + k0);
    acc0 = __builtin_amdgcn_mfma_f32_16x16x32_f16(a0, b, acc0, 0, 0, 0);
    acc1 = __builtin_amdgcn_mfma_f32_16x16x32_f16(a1, b, acc1, 0, 0, 0);
  }
  int p = pbase + nt*16 + row;
  float* op = out + (size_t)n*(64*HW) + p;
  #pragma unroll
  for (int j = 0; j < 4; ++j) {
    int oc0 = mt0*16 + ks*4 + j;
    int oc1 = (mt0+2)*16 + ks*4 + j;
    op[oc0*HW] = acc0[j] + bd[oc0];
    op[oc1*HW] = acc1[j] + bd[oc1];
  }
}

// ---------------- launcher ----------------
extern "C" void kernel_launch(void* const* d_in, const int* in_sizes, int n_in,
                              void* d_out, int out_size, void* d_ws, size_t ws_size,
                              hipStream_t stream)
{
  const float* x   = (const float*)d_in[0];
  // d_in[1] = flow (unused)
  const float* Wi  = (const float*)d_in[2];
  const float* bi  = (const float*)d_in[3];
  const float* ai  = (const float*)d_in[4];
  const float* Wo  = (const float*)d_in[5];
  const float* bo  = (const float*)d_in[6];
  const float* aof = (const float*)d_in[7];
  const float* Wom = (const float*)d_in[8];
  const float* bom = (const float*)d_in[9];
  const float* Wd  = (const float*)d_in[10];
  const float* bd  = (const float*)d_in[11];
  float* out = (float*)d_out;

  // workspace: feat NHWC fp16 | off_feat NHWC fp16 | Wr_dcn | Wr_om | Wr_f | Wr_o
  __half* feat   = (__half*)d_ws;
  __half* offf   = feat + (size_t)NIMG*HW*64;
  __half* Wr_dcn = offf + (size_t)NIMG*HW*64;
  __half* Wr_om  = Wr_dcn + 64*576;
  __half* Wr_f   = Wr_om + 32*576;
  __half* Wr_o   = Wr_f + 64*64;
  // om planes live in d_out: first 27 channel-planes of each image's [64][HW] slice.

  hipLaunchKernelGGL(k_wprep, dim3(248),         dim3(256), 0, stream,
                     Wd, Wom, Wi, Wo, Wr_dcn, Wr_om, Wr_f, Wr_o);
  hipLaunchKernelGGL(k_front, dim3(NIMG*HW/PX),  dim3(256), 0, stream,
                     x, Wr_f, Wr_o, bi, ai, bo, aof, feat, offf);
  hipLaunchKernelGGL(k_om,    dim3(NIMG*HW/PX),  dim3(256), 0, stream, offf, Wr_om, bom, out);
  hipLaunchKernelGGL(k_dcn,   dim3(NIMG*HW/PX),  dim3(256), 0, stream, feat, Wr_dcn, bd, out);
}

// Round 5
// 190.477 us; speedup vs baseline: 8.1421x; 1.3903x over previous
//
#include <hip/hip_runtime.h>
#include <hip/hip_fp16.h>
#include <stdint.h>

typedef __attribute__((ext_vector_type(8))) _Float16 f16x8;
typedef __attribute__((ext_vector_type(4))) float f32x4;

#define NIMG 40      // B*T
#define TFR  5
#define CIN  3
#define HH   64
#define WW   64
#define HW   4096
#define PX   32      // pixels per block (half row)
#define SVS  584     // LDS row stride in halves for deformable v tile
#define RSTR 72      // LDS stride (halves) per region column (144B, 16B-aligned)
#define PPS  72      // LDS row stride for 64-wide front patch

union U32H2 { uint u; __half2 h; };

// ---------------- K0: weight prep (fp16) ----------------
// Wr_dcn[64][576]  kk = k*64+c          <- Wd[oc][c][k]
// Wr_om [32][576]  kk = k*64+c          <- Wom[oc][c][k] (rows 27..31 zero)
// Wr_f  [64][64]   kk = c*9+k (cur)     <- Wi[f][c][k]   (kk 27..63 zero)
// Wr_o  [64][64]   kk 0..26 cur, 27..53 ref <- Wo reordered (54..63 zero)
__global__ __launch_bounds__(256) void k_wprep(
    const float* __restrict__ Wd, const float* __restrict__ Wom,
    const float* __restrict__ Wi, const float* __restrict__ Wo,
    __half* __restrict__ Wr_dcn, __half* __restrict__ Wr_om,
    __half* __restrict__ Wr_f, __half* __restrict__ Wr_o)
{
  int idx = blockIdx.x*256 + threadIdx.x;
  if (idx < 36864) {                         // dcn
    int kk = idx % 576, oc = idx / 576;
    int k = kk >> 6, c = kk & 63;
    Wr_dcn[idx] = __float2half(Wd[oc*576 + c*9 + k]);
  } else if (idx < 36864 + 18432) {          // om
    int q = idx - 36864;
    int kk = q % 576, oc = q / 576;
    int k = kk >> 6, c = kk & 63;
    Wr_om[q] = (oc < 27) ? __float2half(Wom[oc*576 + c*9 + k]) : __float2half(0.f);
  } else if (idx < 36864 + 18432 + 4096) {   // front feat
    int q = idx - 36864 - 18432;
    int kk = q & 63, f = q >> 6;
    Wr_f[q] = (kk < 27) ? __float2half(Wi[f*27 + kk]) : __float2half(0.f);
  } else if (idx < 36864 + 18432 + 8192) {   // front off
    int q = idx - 36864 - 18432 - 4096;
    int kk = q & 63, f = q >> 6;
    float v = 0.f;
    if (kk < 27)       v = Wo[f*54 + 27 + kk];    // cur channels (concat idx 3..5)
    else if (kk < 54)  v = Wo[f*54 + (kk - 27)];  // ref channels (concat idx 0..2)
    Wr_o[q] = __float2half(v);
  }
}

// ---------------- K1: fused feat + off_feat via MFMA [NHWC fp16 out] ----------------
__global__ __launch_bounds__(256) void k_front(
    const float* __restrict__ x,
    const __half* __restrict__ Wr_f, const __half* __restrict__ Wr_o,
    const float* __restrict__ bi, const float* __restrict__ ai,
    const float* __restrict__ bo, const float* __restrict__ aof,
    __half* __restrict__ feat, __half* __restrict__ offf)
{
  __shared__ __align__(16) __half sp[PX*PPS];
  int t = threadIdx.x, blk = blockIdx.x;
  int n = blk >> 7;
  int pbase = (blk & 127) * PX;
  int h = pbase >> 6;
  int wbase = pbase & 63;
  int n0 = (n/TFR)*TFR;
  const float* xc = x + (size_t)n*(CIN*HW);
  const float* xr = x + (size_t)n0*(CIN*HW);

  // im2col patch [32 px][64 kk]: kk 0..26 cur (c*9+k), 27..53 ref, 54..63 zero
  #pragma unroll
  for (int i = 0; i < 8; ++i) {
    int e = i*256 + t;
    int kk = e >> 5, px = e & 31;
    float v = 0.f;
    if (kk < 54) {
      int cur = (kk < 27);
      int kb = cur ? kk : kk - 27;
      int c = kb / 9, k = kb - c*9;
      int y  = h + k/3 - 1;
      int xx = wbase + px + (k - (k/3)*3) - 1;
      if (y >= 0 && y < HH && xx >= 0 && xx < WW)
        v = (cur ? xc : xr)[c*HW + y*WW + xx];
    }
    sp[px*PPS + kk] = __float2half(v);
  }
  __syncthreads();

  int wv = t >> 6, lane = t & 63;
  int row = lane & 15, ks = lane >> 4;
  const __half* af = Wr_f + (wv*16 + row)*64 + ks*8;
  const __half* aw = Wr_o + (wv*16 + row)*64 + ks*8;
  f16x8 af0 = *(const f16x8*)(af);
  f16x8 aw0 = *(const f16x8*)(aw);
  f16x8 aw1 = *(const f16x8*)(aw + 32);
  #pragma unroll
  for (int nt = 0; nt < 2; ++nt) {
    const __half* bp = sp + (nt*16 + row)*PPS + ks*8;
    f16x8 b0 = *(const f16x8*)(bp);
    f16x8 b1 = *(const f16x8*)(bp + 32);
    f32x4 accf = {0.f,0.f,0.f,0.f}, acco = {0.f,0.f,0.f,0.f};
    accf = __builtin_amdgcn_mfma_f32_16x16x32_f16(af0, b0, accf, 0, 0, 0);
    acco = __builtin_amdgcn_mfma_f32_16x16x32_f16(aw0, b0, acco, 0, 0, 0);
    acco = __builtin_amdgcn_mfma_f32_16x16x32_f16(aw1, b1, acco, 0, 0, 0);
    int p  = pbase + nt*16 + row;
    int f0 = wv*16 + ks*4;
    size_t base = ((size_t)n*HW + p)*64 + f0;
    union { ushort4 u; __half b[4]; } pf, po;
    #pragma unroll
    for (int j = 0; j < 4; ++j) {
      float vf = accf[j] + bi[f0+j];
      float aF = ai[f0+j];
      vf = vf >= 0.f ? vf : aF*vf;
      pf.b[j] = __float2half(vf);
      float vo = acco[j] + bo[f0+j];
      float aO = aof[f0+j];
      vo = vo >= 0.f ? vo : aO*vo;
      po.b[j] = __float2half(vo);
    }
    *(ushort4*)(feat + base) = pf.u;
    *(ushort4*)(offf + base) = po.u;
  }
}

// ---------------- K2: fused om-head + modulated deformable conv ----------------
__global__ __launch_bounds__(256) void k_dcn(
    const __half* __restrict__ feat, const __half* __restrict__ offf,
    const __half* __restrict__ Wr_dcn, const __half* __restrict__ Wr_om,
    const float* __restrict__ bom, const float* __restrict__ bd,
    float* __restrict__ out)
{
  __shared__ __align__(16) char smem[PX*SVS*2];   // region (14.7KB) then sv (37.4KB), aliased
  __shared__ float som[27*32];                    // om values for this block's pixels
  __shared__ __align__(16) int4  soff[PX*9];      // 4 corner byte offsets into feat[n]
  __shared__ __align__(16) uint4 swgt[PX*9];      // 4 corner weights as broadcast half2
  __shared__ int sdso[PX*9];                      // LDS dest byte offset per tap
  __half* region = (__half*)smem;
  __half* sv     = (__half*)smem;

  int t = threadIdx.x;
  int blk = blockIdx.x;
  int work = (blk & 7)*640 + (blk >> 3);          // XCD-contiguous: 5 images per XCD
  int n = work >> 7;
  int pbase = (work & 127) * PX;
  int h = pbase >> 6, wbase = pbase & 63;
  int wv = t >> 6, lane = t & 63;
  int row = lane & 15, ks = lane >> 4;

  // ---- step 1: stage off_feat region rows h-1..h+1, cols wbase-1..wbase+32 ----
  const char* ob = (const char*)(offf + (size_t)n*(HW*64));
  for (int u = t; u < 816; u += 256) {            // 3*34*8 uint4 units
    int ry = u / 272;
    int rem = u - ry*272;
    int rx = rem >> 3, q = rem & 7;
    int y = h + ry - 1, xx = wbase + rx - 1;
    uint4 v = make_uint4(0,0,0,0);
    if ((unsigned)y < 64u && (unsigned)xx < 64u)
      v = *(const uint4*)(ob + (((y<<6)+xx)<<7) + q*16);
    *(uint4*)((char*)region + ((ry*34 + rx)*RSTR + q*8)*2) = v;
  }
  __syncthreads();

  // ---- step 2: om = sigmoid/id(Wom * patch) via MFMA, B-frags direct from region ----
  {
    int mt = wv >> 1, nt = wv & 1;
    int pxl = nt*16 + row;
    f32x4 acc = {0.f,0.f,0.f,0.f};
    const __half* ap = Wr_om + (mt*16 + row)*576 + ks*8;
    #pragma unroll
    for (int k0 = 0; k0 < 18; ++k0) {
      int k = k0 >> 1, ky = k/3, kx = k - ky*3;
      int c0 = (k0 & 1)*32;
      f16x8 a = *(const f16x8*)(ap + k0*32);
      f16x8 b = *(const f16x8*)(region + (ky*34 + pxl + kx)*RSTR + c0 + ks*8);
      acc = __builtin_amdgcn_mfma_f32_16x16x32_f16(a, b, acc, 0, 0, 0);
    }
    #pragma unroll
    for (int j = 0; j < 4; ++j) {
      int oc = mt*16 + ks*4 + j;
      if (oc < 27) {
        float r = acc[j] + bom[oc];
        if (oc >= 18) r = 1.f/(1.f + __expf(-r));
        som[oc*32 + pxl] = r;
      }
    }
  }
  __syncthreads();

  // ---- step 3: per (pixel, tap) bilinear params from som ----
  for (int e = t; e < PX*9; e += 256) {
    int px = e / 9, k = e - px*9;
    int p = pbase + px;
    int hh = p >> 6, w = p & 63;
    float dy = som[(2*k)*32 + px];
    float dx = som[(2*k+1)*32 + px];
    float m  = som[(18+k)*32 + px];
    float py = (float)(hh + (k/3) - 1) + dy;
    float qx = (float)(w + (k - (k/3)*3) - 1) + dx;
    float y0f = floorf(py), x0f = floorf(qx);
    float wy = py - y0f, wx = px - x0f;
    wx = qx - x0f;
    int y0 = (int)y0f, x0 = (int)x0f;
    int y1 = y0 + 1, x1 = x0 + 1;
    float w00 = (1.f-wy)*(1.f-wx)*m;
    float w01 = (1.f-wy)*wx*m;
    float w10 = wy*(1.f-wx)*m;
    float w11 = wy*wx*m;
    if (y0 < 0 || y0 >= HH) { w00 = 0.f; w01 = 0.f; }
    if (y1 < 0 || y1 >= HH) { w10 = 0.f; w11 = 0.f; }
    if (x0 < 0 || x0 >= WW) { w00 = 0.f; w10 = 0.f; }
    if (x1 < 0 || x1 >= WW) { w01 = 0.f; w11 = 0.f; }
    int y0c = min(max(y0,0),HH-1), y1c = min(max(y1,0),HH-1);
    int x0c = min(max(x0,0),WW-1), x1c = min(max(x1,0),WW-1);
    soff[e] = make_int4((((y0c<<6)+x0c)<<7), (((y0c<<6)+x1c)<<7),
                        (((y1c<<6)+x0c)<<7), (((y1c<<6)+x1c)<<7));
    U32H2 u00, u01, u10, u11;
    u00.h = __float2half2_rn(w00); u01.h = __float2half2_rn(w01);
    u10.h = __float2half2_rn(w10); u11.h = __float2half2_rn(w11);
    swgt[e] = make_uint4(u00.u, u01.u, u10.u, u11.u);
    sdso[e] = (px*SVS + k*64)*2;
  }
  __syncthreads();

  // ---- step 4: deformable gather, uint4 per lane (8 lanes per tap-corner row) ----
  const char* fb = (const char*)(feat + (size_t)n*(HW*64));
  #pragma unroll 3
  for (int i = 0; i < 9; ++i) {                  // 2304 uint4 units / 256 threads
    int u = i*256 + t;
    int tap = u >> 3, q = u & 7, qb = q*16;
    int4  off = soff[tap];
    uint4 wq  = swgt[tap];
    int   dso = sdso[tap];
    uint4 c00 = *(const uint4*)(fb + off.x + qb);
    uint4 c01 = *(const uint4*)(fb + off.y + qb);
    uint4 c10 = *(const uint4*)(fb + off.z + qb);
    uint4 c11 = *(const uint4*)(fb + off.w + qb);
    U32H2 W00, W01, W10, W11;
    W00.u = wq.x; W01.u = wq.y; W10.u = wq.z; W11.u = wq.w;
    uint4 r;
#define BILIN(comp) { U32H2 a0,a1,a2,a3,res;                                    \
    a0.u = c00.comp; a1.u = c01.comp; a2.u = c10.comp; a3.u = c11.comp;         \
    __half2 v = __hmul2(W00.h, a0.h); v = __hfma2(W01.h, a1.h, v);              \
    v = __hfma2(W10.h, a2.h, v);      v = __hfma2(W11.h, a3.h, v);              \
    res.h = v; r.comp = res.u; }
    BILIN(x) BILIN(y) BILIN(z) BILIN(w)
#undef BILIN
    *(uint4*)((char*)sv + dso + qb) = r;
  }
  __syncthreads();

  // ---- step 5: MFMA  D[oc][px] = sum_kk Wd[oc][kk] * v[px][kk] ----
  int nt = wv & 1, mt0 = wv >> 1;
  f32x4 acc0 = {0.f,0.f,0.f,0.f}, acc1 = {0.f,0.f,0.f,0.f};
  const __half* a0p = Wr_dcn + (mt0*16 + row)*576 + ks*8;
  const __half* a1p = Wr_dcn + ((mt0+2)*16 + row)*576 + ks*8;
  const __half* bp  = sv + (nt*16 + row)*SVS + ks*8;
  for (int k0 = 0; k0 < 576; k0 += 32) {
    f16x8 a0 = *(const f16x8*)(a0p + k0);
    f16x8 a1 = *(const f16x8*)(a1p + k0);
    f16x8 b  = *(const f16x8*)(bp + k0);
    acc0 = __builtin_amdgcn_mfma_f32_16x16x32_f16(a0, b, acc0, 0, 0, 0);
    acc1 = __builtin_amdgcn_mfma_f32_16x16x32_f16(a1, b, acc1, 0, 0, 0);
  }
  int p = pbase + nt*16 + row;
  float* op = out + (size_t)n*(64*HW) + p;
  #pragma unroll
  for (int j = 0; j < 4; ++j) {
    int oc0 = mt0*16 + ks*4 + j;
    int oc1 = (mt0+2)*16 + ks*4 + j;
    op[oc0*HW] = acc0[j] + bd[oc0];
    op[oc1*HW] = acc1[j] + bd[oc1];
  }
}

// ---------------- launcher ----------------
extern "C" void kernel_launch(void* const* d_in, const int* in_sizes, int n_in,
                              void* d_out, int out_size, void* d_ws, size_t ws_size,
                              hipStream_t stream)
{
  const float* x   = (const float*)d_in[0];
  // d_in[1] = flow (unused)
  const float* Wi  = (const float*)d_in[2];
  const float* bi  = (const float*)d_in[3];
  const float* ai  = (const float*)d_in[4];
  const float* Wo  = (const float*)d_in[5];
  const float* bo  = (const float*)d_in[6];
  const float* aof = (const float*)d_in[7];
  const float* Wom = (const float*)d_in[8];
  const float* bom = (const float*)d_in[9];
  const float* Wd  = (const float*)d_in[10];
  const float* bd  = (const float*)d_in[11];
  float* out = (float*)d_out;

  // workspace: feat NHWC fp16 | off_feat NHWC fp16 | Wr_dcn | Wr_om | Wr_f | Wr_o
  __half* feat   = (__half*)d_ws;
  __half* offf   = feat + (size_t)NIMG*HW*64;
  __half* Wr_dcn = offf + (size_t)NIMG*HW*64;
  __half* Wr_om  = Wr_dcn + 64*576;
  __half* Wr_f   = Wr_om + 32*576;
  __half* Wr_o   = Wr_f + 64*64;

  hipLaunchKernelGGL(k_wprep, dim3(248),         dim3(256), 0, stream,
                     Wd, Wom, Wi, Wo, Wr_dcn, Wr_om, Wr_f, Wr_o);
  hipLaunchKernelGGL(k_front, dim3(NIMG*HW/PX),  dim3(256), 0, stream,
                     x, Wr_f, Wr_o, bi, ai, bo, aof, feat, offf);
  hipLaunchKernelGGL(k_dcn,   dim3(NIMG*HW/PX),  dim3(256), 0, stream,
                     feat, offf, Wr_dcn, Wr_om, bom, bd, out);
}

// Round 6
// 186.189 us; speedup vs baseline: 8.3296x; 1.0230x over previous
//
#include <hip/hip_runtime.h>
#include <hip/hip_fp16.h>
#include <stdint.h>

typedef __attribute__((ext_vector_type(8))) _Float16 f16x8;
typedef __attribute__((ext_vector_type(4))) float f32x4;

#define NIMG 40      // B*T
#define TFR  5
#define CIN  3
#define HH   64
#define WW   64
#define HW   4096
#define PX   32      // pixels per block (half row)
#define RSTR 72      // LDS stride (halves) per region column (144B, 16B-aligned)
#define BSTR 72      // LDS stride (halves) per pixel row in tap buffer
#define PPS  72      // LDS row stride for 64-wide front patch

union U32H2 { uint u; __half2 h; };

// ---------------- K0: weight prep (fp16) ----------------
// Wr_dcn[64][576]  kk = k*64+c          <- Wd[oc][c][k]
// Wr_om [32][576]  kk = k*64+c          <- Wom[oc][c][k] (rows 27..31 zero)
// Wr_f  [64][64]   kk = c*9+k (cur)     <- Wi[f][c][k]   (kk 27..63 zero)
// Wr_o  [64][64]   kk 0..26 cur, 27..53 ref <- Wo reordered (54..63 zero)
__global__ __launch_bounds__(256) void k_wprep(
    const float* __restrict__ Wd, const float* __restrict__ Wom,
    const float* __restrict__ Wi, const float* __restrict__ Wo,
    __half* __restrict__ Wr_dcn, __half* __restrict__ Wr_om,
    __half* __restrict__ Wr_f, __half* __restrict__ Wr_o)
{
  int idx = blockIdx.x*256 + threadIdx.x;
  if (idx < 36864) {                         // dcn
    int kk = idx % 576, oc = idx / 576;
    int k = kk >> 6, c = kk & 63;
    Wr_dcn[idx] = __float2half(Wd[oc*576 + c*9 + k]);
  } else if (idx < 36864 + 18432) {          // om
    int q = idx - 36864;
    int kk = q % 576, oc = q / 576;
    int k = kk >> 6, c = kk & 63;
    Wr_om[q] = (oc < 27) ? __float2half(Wom[oc*576 + c*9 + k]) : __float2half(0.f);
  } else if (idx < 36864 + 18432 + 4096) {   // front feat
    int q = idx - 36864 - 18432;
    int kk = q & 63, f = q >> 6;
    Wr_f[q] = (kk < 27) ? __float2half(Wi[f*27 + kk]) : __float2half(0.f);
  } else if (idx < 36864 + 18432 + 8192) {   // front off
    int q = idx - 36864 - 18432 - 4096;
    int kk = q & 63, f = q >> 6;
    float v = 0.f;
    if (kk < 27)       v = Wo[f*54 + 27 + kk];    // cur channels (concat idx 3..5)
    else if (kk < 54)  v = Wo[f*54 + (kk - 27)];  // ref channels (concat idx 0..2)
    Wr_o[q] = __float2half(v);
  }
}

// ---------------- K1: fused feat + off_feat via MFMA [NHWC fp16 out] ----------------
__global__ __launch_bounds__(256) void k_front(
    const float* __restrict__ x,
    const __half* __restrict__ Wr_f, const __half* __restrict__ Wr_o,
    const float* __restrict__ bi, const float* __restrict__ ai,
    const float* __restrict__ bo, const float* __restrict__ aof,
    __half* __restrict__ feat, __half* __restrict__ offf)
{
  __shared__ __align__(16) __half sp[PX*PPS];
  int t = threadIdx.x, blk = blockIdx.x;
  int n = blk >> 7;
  int pbase = (blk & 127) * PX;
  int h = pbase >> 6;
  int wbase = pbase & 63;
  int n0 = (n/TFR)*TFR;
  const float* xc = x + (size_t)n*(CIN*HW);
  const float* xr = x + (size_t)n0*(CIN*HW);

  // im2col patch [32 px][64 kk]: kk 0..26 cur (c*9+k), 27..53 ref, 54..63 zero
  #pragma unroll
  for (int i = 0; i < 8; ++i) {
    int e = i*256 + t;
    int kk = e >> 5, px = e & 31;
    float v = 0.f;
    if (kk < 54) {
      int cur = (kk < 27);
      int kb = cur ? kk : kk - 27;
      int c = kb / 9, k = kb - c*9;
      int y  = h + k/3 - 1;
      int xx = wbase + px + (k - (k/3)*3) - 1;
      if (y >= 0 && y < HH && xx >= 0 && xx < WW)
        v = (cur ? xc : xr)[c*HW + y*WW + xx];
    }
    sp[px*PPS + kk] = __float2half(v);
  }
  __syncthreads();

  int wv = t >> 6, lane = t & 63;
  int row = lane & 15, ks = lane >> 4;
  const __half* af = Wr_f + (wv*16 + row)*64 + ks*8;
  const __half* aw = Wr_o + (wv*16 + row)*64 + ks*8;
  f16x8 af0 = *(const f16x8*)(af);
  f16x8 aw0 = *(const f16x8*)(aw);
  f16x8 aw1 = *(const f16x8*)(aw + 32);
  #pragma unroll
  for (int nt = 0; nt < 2; ++nt) {
    const __half* bp = sp + (nt*16 + row)*PPS + ks*8;
    f16x8 b0 = *(const f16x8*)(bp);
    f16x8 b1 = *(const f16x8*)(bp + 32);
    f32x4 accf = {0.f,0.f,0.f,0.f}, acco = {0.f,0.f,0.f,0.f};
    accf = __builtin_amdgcn_mfma_f32_16x16x32_f16(af0, b0, accf, 0, 0, 0);
    acco = __builtin_amdgcn_mfma_f32_16x16x32_f16(aw0, b0, acco, 0, 0, 0);
    acco = __builtin_amdgcn_mfma_f32_16x16x32_f16(aw1, b1, acco, 0, 0, 0);
    int p  = pbase + nt*16 + row;
    int f0 = wv*16 + ks*4;
    size_t base = ((size_t)n*HW + p)*64 + f0;
    union { ushort4 u; __half b[4]; } pf, po;
    #pragma unroll
    for (int j = 0; j < 4; ++j) {
      float vf = accf[j] + bi[f0+j];
      float aF = ai[f0+j];
      vf = vf >= 0.f ? vf : aF*vf;
      pf.b[j] = __float2half(vf);
      float vo = acco[j] + bo[f0+j];
      float aO = aof[f0+j];
      vo = vo >= 0.f ? vo : aO*vo;
      po.b[j] = __float2half(vo);
    }
    *(ushort4*)(feat + base) = pf.u;
    *(ushort4*)(offf + base) = po.u;
  }
}

// ---------------- K2: fused om-head + DCN, per-tap double-buffered pipeline ----------------
__global__ __launch_bounds__(256) void k_dcn(
    const __half* __restrict__ feat, const __half* __restrict__ offf,
    const __half* __restrict__ Wr_dcn, const __half* __restrict__ Wr_om,
    const float* __restrict__ bom, const float* __restrict__ bd,
    float* __restrict__ out)
{
  __shared__ __align__(16) char smem[3*34*RSTR*2];  // region (14.7KB); aliases 2 tap bufs
  __shared__ float som[27*32];                      // om values for this block's pixels
  __shared__ __align__(16) int4  soff[PX*9];        // 4 corner byte offsets into feat[n]
  __shared__ __align__(16) uint4 swgt[PX*9];        // 4 corner weights as broadcast half2
  __half* region = (__half*)smem;
  __half* buf[2] = { (__half*)smem, (__half*)(smem + PX*BSTR*2) };

  int t = threadIdx.x;
  int blk = blockIdx.x;
  int work = (blk & 7)*640 + (blk >> 3);            // XCD-contiguous: 5 images per XCD
  int n = work >> 7;
  int pbase = (work & 127) * PX;
  int h = pbase >> 6, wbase = pbase & 63;
  int wv = t >> 6, lane = t & 63;
  int row = lane & 15, ks = lane >> 4;

  // ---- step 1: stage off_feat region rows h-1..h+1, cols wbase-1..wbase+32 ----
  const char* ob = (const char*)(offf + (size_t)n*(HW*64));
  for (int u = t; u < 816; u += 256) {              // 3*34*8 uint4 units
    int ry = u / 272;
    int rem = u - ry*272;
    int rx = rem >> 3, q = rem & 7;
    int y = h + ry - 1, xx = wbase + rx - 1;
    uint4 v = make_uint4(0,0,0,0);
    if ((unsigned)y < 64u && (unsigned)xx < 64u)
      v = *(const uint4*)(ob + (((y<<6)+xx)<<7) + q*16);
    *(uint4*)((char*)region + ((ry*34 + rx)*RSTR + q*8)*2) = v;
  }
  __syncthreads();

  // ---- step 2: om = sigmoid/id(Wom * patch) via MFMA, B-frags direct from region ----
  {
    int mt = wv >> 1, nt = wv & 1;
    int pxl = nt*16 + row;
    f32x4 acc = {0.f,0.f,0.f,0.f};
    const __half* ap = Wr_om + (mt*16 + row)*576 + ks*8;
    #pragma unroll
    for (int k0 = 0; k0 < 18; ++k0) {
      int k = k0 >> 1, ky = k/3, kx = k - ky*3;
      int c0 = (k0 & 1)*32;
      f16x8 a = *(const f16x8*)(ap + k0*32);
      f16x8 b = *(const f16x8*)(region + (ky*34 + pxl + kx)*RSTR + c0 + ks*8);
      acc = __builtin_amdgcn_mfma_f32_16x16x32_f16(a, b, acc, 0, 0, 0);
    }
    #pragma unroll
    for (int j = 0; j < 4; ++j) {
      int oc = mt*16 + ks*4 + j;
      if (oc < 27) {
        float r = acc[j] + bom[oc];
        if (oc >= 18) r = 1.f/(1.f + __expf(-r));
        som[oc*32 + pxl] = r;
      }
    }
  }
  __syncthreads();

  // ---- step 3: per (pixel, tap) bilinear params from som ----
  for (int e = t; e < PX*9; e += 256) {
    int px = e / 9, k = e - px*9;
    int p = pbase + px;
    int hh = p >> 6, w = p & 63;
    float dy = som[(2*k)*32 + px];
    float dx = som[(2*k+1)*32 + px];
    float m  = som[(18+k)*32 + px];
    float py = (float)(hh + (k/3) - 1) + dy;
    float qx = (float)(w + (k - (k/3)*3) - 1) + dx;
    float y0f = floorf(py), x0f = floorf(qx);
    float wy = py - y0f, wx = qx - x0f;
    int y0 = (int)y0f, x0 = (int)x0f;
    int y1 = y0 + 1, x1 = x0 + 1;
    float w00 = (1.f-wy)*(1.f-wx)*m;
    float w01 = (1.f-wy)*wx*m;
    float w10 = wy*(1.f-wx)*m;
    float w11 = wy*wx*m;
    if (y0 < 0 || y0 >= HH) { w00 = 0.f; w01 = 0.f; }
    if (y1 < 0 || y1 >= HH) { w10 = 0.f; w11 = 0.f; }
    if (x0 < 0 || x0 >= WW) { w00 = 0.f; w10 = 0.f; }
    if (x1 < 0 || x1 >= WW) { w01 = 0.f; w11 = 0.f; }
    int y0c = min(max(y0,0),HH-1), y1c = min(max(y1,0),HH-1);
    int x0c = min(max(x0,0),WW-1), x1c = min(max(x1,0),WW-1);
    soff[e] = make_int4((((y0c<<6)+x0c)<<7), (((y0c<<6)+x1c)<<7),
                        (((y1c<<6)+x0c)<<7), (((y1c<<6)+x1c)<<7));
    U32H2 u00, u01, u10, u11;
    u00.h = __float2half2_rn(w00); u01.h = __float2half2_rn(w01);
    u10.h = __float2half2_rn(w10); u11.h = __float2half2_rn(w11);
    swgt[e] = make_uint4(u00.u, u01.u, u10.u, u11.u);
  }
  __syncthreads();

  // ---- step 4: 9-tap pipeline: stage tap k+1 around MFMA on tap k ----
  const char* fb = (const char*)(feat + (size_t)n*(HW*64));
  int spx = t >> 3, sq = t & 7;                     // staging role: (pixel, quad)
  int sqb = sq*16;
  int nt = wv & 1, mt0 = wv >> 1;                   // MFMA role
  f32x4 acc0 = {0.f,0.f,0.f,0.f}, acc1 = {0.f,0.f,0.f,0.f};
  const __half* a00p = Wr_dcn + (mt0*16 + row)*576 + ks*8;
  const __half* a10p = Wr_dcn + ((mt0+2)*16 + row)*576 + ks*8;
  const __half* bpix = (const __half*)((char*)0 + (nt*16 + row)*BSTR*2 + ks*16);

  // prologue: stage tap 0 into buf0
  {
    int e = spx*9 + 0;
    int4  off = soff[e];
    uint4 wq  = swgt[e];
    uint4 c00 = *(const uint4*)(fb + off.x + sqb);
    uint4 c01 = *(const uint4*)(fb + off.y + sqb);
    uint4 c10 = *(const uint4*)(fb + off.z + sqb);
    uint4 c11 = *(const uint4*)(fb + off.w + sqb);
    U32H2 W00, W01, W10, W11;
    W00.u = wq.x; W01.u = wq.y; W10.u = wq.z; W11.u = wq.w;
    uint4 r;
#define BILIN(comp) { U32H2 a0v,a1v,a2v,a3v,res;                                \
    a0v.u = c00.comp; a1v.u = c01.comp; a2v.u = c10.comp; a3v.u = c11.comp;     \
    __half2 v = __hmul2(W00.h, a0v.h); v = __hfma2(W01.h, a1v.h, v);            \
    v = __hfma2(W10.h, a2v.h, v);      v = __hfma2(W11.h, a3v.h, v);            \
    res.h = v; r.comp = res.u; }
    BILIN(x) BILIN(y) BILIN(z) BILIN(w)
    *(uint4*)((char*)buf[0] + (spx*BSTR)*2 + sqb) = r;
  }
  __syncthreads();

  #pragma unroll
  for (int k = 0; k < 9; ++k) {
    const __half* cur = buf[k & 1];
    // issue next tap's corner loads early (latency hides under MFMA below)
    uint4 c00, c01, c10, c11; uint4 wq;
    if (k < 8) {
      int e = spx*9 + k + 1;
      int4 off = soff[e];
      wq = swgt[e];
      c00 = *(const uint4*)(fb + off.x + sqb);
      c01 = *(const uint4*)(fb + off.y + sqb);
      c10 = *(const uint4*)(fb + off.z + sqb);
      c11 = *(const uint4*)(fb + off.w + sqb);
    }
    // MFMA on tap k
    {
      const __half* bp = (const __half*)((const char*)cur + (size_t)bpix);
      f16x8 b0 = *(const f16x8*)(bp);
      f16x8 b1 = *(const f16x8*)(bp + 32);
      f16x8 a00 = *(const f16x8*)(a00p + k*64);
      f16x8 a01 = *(const f16x8*)(a00p + k*64 + 32);
      f16x8 a10 = *(const f16x8*)(a10p + k*64);
      f16x8 a11 = *(const f16x8*)(a10p + k*64 + 32);
      acc0 = __builtin_amdgcn_mfma_f32_16x16x32_f16(a00, b0, acc0, 0, 0, 0);
      acc0 = __builtin_amdgcn_mfma_f32_16x16x32_f16(a01, b1, acc0, 0, 0, 0);
      acc1 = __builtin_amdgcn_mfma_f32_16x16x32_f16(a10, b0, acc1, 0, 0, 0);
      acc1 = __builtin_amdgcn_mfma_f32_16x16x32_f16(a11, b1, acc1, 0, 0, 0);
    }
    if (k < 8) {
      U32H2 W00, W01, W10, W11;
      W00.u = wq.x; W01.u = wq.y; W10.u = wq.z; W11.u = wq.w;
      uint4 r;
      BILIN(x) BILIN(y) BILIN(z) BILIN(w)
      *(uint4*)((char*)buf[(k+1) & 1] + (spx*BSTR)*2 + sqb) = r;
    }
    __syncthreads();
  }
#undef BILIN

  // ---- epilogue ----
  int p = pbase + nt*16 + row;
  float* op = out + (size_t)n*(64*HW) + p;
  #pragma unroll
  for (int j = 0; j < 4; ++j) {
    int oc0 = mt0*16 + ks*4 + j;
    int oc1 = (mt0+2)*16 + ks*4 + j;
    op[oc0*HW] = acc0[j] + bd[oc0];
    op[oc1*HW] = acc1[j] + bd[oc1];
  }
}

// ---------------- launcher ----------------
extern "C" void kernel_launch(void* const* d_in, const int* in_sizes, int n_in,
                              void* d_out, int out_size, void* d_ws, size_t ws_size,
                              hipStream_t stream)
{
  const float* x   = (const float*)d_in[0];
  // d_in[1] = flow (unused)
  const float* Wi  = (const float*)d_in[2];
  const float* bi  = (const float*)d_in[3];
  const float* ai  = (const float*)d_in[4];
  const float* Wo  = (const float*)d_in[5];
  const float* bo  = (const float*)d_in[6];
  const float* aof = (const float*)d_in[7];
  const float* Wom = (const float*)d_in[8];
  const float* bom = (const float*)d_in[9];
  const float* Wd  = (const float*)d_in[10];
  const float* bd  = (const float*)d_in[11];
  float* out = (float*)d_out;

  // workspace: feat NHWC fp16 | off_feat NHWC fp16 | Wr_dcn | Wr_om | Wr_f | Wr_o
  __half* feat   = (__half*)d_ws;
  __half* offf   = feat + (size_t)NIMG*HW*64;
  __half* Wr_dcn = offf + (size_t)NIMG*HW*64;
  __half* Wr_om  = Wr_dcn + 64*576;
  __half* Wr_f   = Wr_om + 32*576;
  __half* Wr_o   = Wr_f + 64*64;

  hipLaunchKernelGGL(k_wprep, dim3(248),         dim3(256), 0, stream,
                     Wd, Wom, Wi, Wo, Wr_dcn, Wr_om, Wr_f, Wr_o);
  hipLaunchKernelGGL(k_front, dim3(NIMG*HW/PX),  dim3(256), 0, stream,
                     x, Wr_f, Wr_o, bi, ai, bo, aof, feat, offf);
  hipLaunchKernelGGL(k_dcn,   dim3(NIMG*HW/PX),  dim3(256), 0, stream,
                     feat, offf, Wr_dcn, Wr_om, bom, bd, out);
}